// Round 1
// baseline (6719.704 us; speedup 1.0000x reference)
//
#include <hip/hip_runtime.h>
#include <cstdint>
#include <cstddef>

// ---------------------------------------------------------------------------
// Trainer_91216515433187: BN + Dense + LSTM encoder (1024 steps) + 35-step
// autoregressive LSTM decoder.
//
// Round 2 design: ONE workgroup (512 thr, 8 waves) per batch-tile of 16 rows.
// No inter-workgroup communication at all (prev version lost ~3.5 us/step to
// agent-scope exchange; WRITE_SIZE 137MB). h (16x256 f16) lives in LDS with an
// XOR bank swizzle; recurrent weights split 3 ways per wave:
//   s8 0..3 -> registers (128 VGPR), s8 4,6 -> LDS pool (128KB, re-read each
//   step), s8 5,7 -> streamed from L2 each step (issued early, overlaps).
// Two __syncthreads per step; gate VALU computed before barrier 1 so it
// overlaps other waves' streaming. Decoder token/bias folded into a packed
// affine MFMA (A=[t0,t1,1,0..]); W_mlp pred MFMA on wave 0 only.
// ---------------------------------------------------------------------------

typedef _Float16 h8 __attribute__((ext_vector_type(8)));
typedef _Float16 h4 __attribute__((ext_vector_type(4)));
typedef float f4 __attribute__((ext_vector_type(4)));
typedef float f2 __attribute__((ext_vector_type(2)));

// ws byte offsets (precompute outputs; layout kept from round 1)
#define WS_RKT    262400    // 1024 cols x 256 k f16 = 524288 B
#define WS_WEFF   786688    // 1024 cols x 8 f f16 = 16384 B
#define WS_WMLP   803072    // 2 e x 256 k f16 = 1024 B
#define WS_DEFF   804096    // 2 x 1024 f32 = 8192 B
#define WS_ZB     812288    // 1024 f32
#define WS_DB     816384    // 1024 f32

// LDS layout
#define LB_BP   0                   // B-frag pool: 8w x 16frag x 64lane x 16B = 131072
#define LB_H    131072              // h: 16 rows x 256 k f16, XOR-swizzled = 8192
#define LB_UN   139264              // union: enc_aff(16384) | dec_aff(8192)+wm(1024)+tok(128)
#define LB_DEC  LB_UN
#define LB_WM   (LB_UN + 8192)
#define LB_TOK  (LB_UN + 9216)
#define LDS_SZ  (LB_UN + 16384)    // 155648 B

__device__ __forceinline__ float fexp2(float x){
#if __has_builtin(__builtin_amdgcn_exp2f)
  return __builtin_amdgcn_exp2f(x);
#else
  return exp2f(x);
#endif
}
__device__ __forceinline__ float frcp(float x){
#if __has_builtin(__builtin_amdgcn_rcpf)
  return __builtin_amdgcn_rcpf(x);
#else
  return 1.f / x;
#endif
}
__device__ __forceinline__ float sigf(float x){
  return frcp(1.f + fexp2(-1.44269504f * x));
}
__device__ __forceinline__ float tanh_f(float x){
  return 2.f * frcp(1.f + fexp2(-2.88539008f * x)) - 1.f;
}

// grid 1024 x 256 threads  (unchanged from round 1 — known correct)
__global__ void precompute_k(const float* __restrict__ bn_gamma,
                             const float* __restrict__ bn_beta,
                             const float* __restrict__ bn_mean,
                             const float* __restrict__ bn_var,
                             const float* __restrict__ W_pulse,   // (8,256)
                             const float* __restrict__ b_pulse,   // (256)
                             const float* __restrict__ lstm_k,    // (256,1024)
                             const float* __restrict__ lstm_rk,   // (256,1024)
                             const float* __restrict__ lstm_b,    // (1024)
                             const float* __restrict__ W_eis,     // (2,256)
                             const float* __restrict__ b_eis,     // (256)
                             const float* __restrict__ W_mlp,     // (256,2)
                             _Float16* __restrict__ rkT,          // [col][k]
                             _Float16* __restrict__ WeffT,        // [col][f]
                             _Float16* __restrict__ WmlpT,        // [e][k]
                             float* __restrict__ Deff,            // [e][col]
                             float* __restrict__ zbias,
                             float* __restrict__ dbias)
{
  int gid = blockIdx.x * 256 + threadIdx.x;   // 0..262143
  {
    int col = gid >> 8;
    int k   = gid & 255;
    rkT[col * 256 + k] = (_Float16)lstm_rk[k * 1024 + col];
  }
  if (gid < 512) {
    int e = gid >> 8, k = gid & 255;
    WmlpT[e * 256 + k] = (_Float16)W_mlp[k * 2 + e];
  }
  if (gid < 1024) {
    int j = gid;
    float a[8], bv[8];
#pragma unroll
    for (int f = 0; f < 8; ++f) {
      float af = bn_gamma[f] * rsqrtf(bn_var[f] + 1e-3f);
      a[f]  = af;
      bv[f] = bn_beta[f] - bn_mean[f] * af;
    }
    float m[8] = {0,0,0,0,0,0,0,0};
    float d0 = 0.f, d1 = 0.f, zb2 = 0.f, db2 = 0.f;
    for (int k = 0; k < 256; ++k) {
      float lk = lstm_k[k * 1024 + j];
#pragma unroll
      for (int f = 0; f < 8; ++f) m[f] += W_pulse[f * 256 + k] * lk;
      d0  += W_eis[k]       * lk;
      d1  += W_eis[256 + k] * lk;
      zb2 += b_pulse[k] * lk;
      db2 += b_eis[k]   * lk;
    }
    float zb = lstm_b[j] + zb2;
#pragma unroll
    for (int f = 0; f < 8; ++f) {
      zb += bv[f] * m[f];
      WeffT[j * 8 + f] = (_Float16)(a[f] * m[f]);
    }
    zbias[j] = zb;
    dbias[j] = lstm_b[j] + db2;
    Deff[j]        = d0;
    Deff[1024 + j] = d1;
  }
}

// global B-frag load: (zcol,s8) 16B at rkT + zcol*512 + s8*64 + quad*16 bytes
#define GFRAG(s8_, u_, g_)                                                     \
  (*reinterpret_cast<const h8*>(                                               \
      rkTb + (gbo + (uint32_t)((g_) * 131072 + (u_) * 8192 + (s8_) * 64))))

// Main per-step MFMA block: acc_[2][4] += h @ rk  (h from LDS, weights mixed)
#define STEP_MFMAS(acc_)                                                       \
  {                                                                            \
    h8 gq[2][4];                                                               \
    _Pragma("unroll") for (int uu = 0; uu < 2; ++uu)                           \
    _Pragma("unroll") for (int gg = 0; gg < 4; ++gg)                           \
      gq[uu][gg] = GFRAG(5, uu, gg);                                           \
    _Pragma("unroll")                                                          \
    for (int s8 = 0; s8 < 8; ++s8) {                                           \
      h8 ha = *reinterpret_cast<const h8*>(                                    \
          &smem[LB_H + ((hbase + (uint32_t)(s8 * 64)) ^ hswz)]);               \
      _Pragma("unroll") for (int uu = 0; uu < 2; ++uu)                         \
      _Pragma("unroll") for (int gg = 0; gg < 4; ++gg) {                       \
        h8 wb;                                                                 \
        if (s8 < 4)                                                            \
          wb = Wreg[s8][uu][gg];                                               \
        else if (s8 == 4)                                                      \
          wb = *reinterpret_cast<const h8*>(                                   \
              &smem[LB_BP + bpb + (uint32_t)((uu * 4 + gg) * 1024)]);          \
        else if (s8 == 6)                                                      \
          wb = *reinterpret_cast<const h8*>(                                   \
              &smem[LB_BP + bpb + (uint32_t)((8 + uu * 4 + gg) * 1024)]);      \
        else                                                                   \
          wb = gq[uu][gg];                                                     \
        acc_[uu][gg] = __builtin_amdgcn_mfma_f32_16x16x32_f16(                 \
            ha, wb, acc_[uu][gg], 0, 0, 0);                                    \
      }                                                                        \
      if (s8 == 5) {                                                           \
        uint32_t gbo7 = gbo;                                                   \
        /* data-dep: keep s8=7 loads from hoisting to step start (VGPRs) */    \
        asm volatile("" : "+v"(gbo7) : "v"(acc_[0][0]));                       \
        _Pragma("unroll") for (int uu = 0; uu < 2; ++uu)                       \
        _Pragma("unroll") for (int gg = 0; gg < 4; ++gg)                       \
          gq[uu][gg] = *reinterpret_cast<const h8*>(                           \
              rkTb + (gbo7 + (uint32_t)(gg * 131072 + uu * 8192 + 7 * 64)));   \
      }                                                                        \
    }                                                                          \
  }

// gates (VALU, pre-barrier) then swizzled h store (post-barrier)
#define GATES_AND_STORE(acc_)                                                  \
  {                                                                            \
    _Float16 hvv[2][4];                                                        \
    _Pragma("unroll") for (int uu = 0; uu < 2; ++uu)                           \
    _Pragma("unroll") for (int r = 0; r < 4; ++r) {                            \
      float iv = sigf(acc_[uu][0][r]);                                         \
      float fv = sigf(acc_[uu][1][r]);                                         \
      float gv = tanh_f(acc_[uu][2][r]);                                       \
      float ov = sigf(acc_[uu][3][r]);                                         \
      float cc = fv * cf[uu][r] + iv * gv;                                     \
      cf[uu][r] = cc;                                                          \
      hvv[uu][r] = (_Float16)(ov * tanh_f(cc));                                \
    }                                                                          \
    __syncthreads(); /* all waves done READING h */                            \
    _Pragma("unroll") for (int uu = 0; uu < 2; ++uu)                           \
    _Pragma("unroll") for (int r = 0; r < 4; ++r) {                            \
      int row = quad * 4 + r;                                                  \
      uint32_t wa = (uint32_t)(row * 512 + (w * 32 + uu * 16 + n) * 2) ^       \
                    (uint32_t)((row & 7) << 4);                                \
      *reinterpret_cast<_Float16*>(&smem[LB_H + wa]) = hvv[uu][r];             \
    }                                                                          \
    __syncthreads(); /* h(t+1) visible */                                      \
  }

// 16 blocks x 512 threads; one block per 16 batch rows; 1 block/CU.
__global__ __launch_bounds__(512, 2)
void lstm_main_k(const float* __restrict__ pulse,      // (256,1024,8)
                 const float* __restrict__ embed,      // (1,2)
                 const float* __restrict__ b_mlp,      // (2)
                 const float* __restrict__ scale_w,    // (2)
                 const float* __restrict__ scale_b,    // (2)
                 const _Float16* __restrict__ rkT,
                 const _Float16* __restrict__ WeffT,
                 const _Float16* __restrict__ WmlpT,
                 const float* __restrict__ Deff,
                 const float* __restrict__ zbias,
                 const float* __restrict__ dbias,
                 float* __restrict__ out)              // (256,35,2)
{
  __shared__ alignas(16) char smem[LDS_SZ];

  const int tid  = threadIdx.x;
  const int w    = tid >> 6;
  const int lane = tid & 63;
  const int n    = lane & 15;
  const int quad = lane >> 4;
  const int b0   = blockIdx.x * 16;

  const char* rkTb = reinterpret_cast<const char*>(rkT);
  // per-lane byte offset into rkT for (col = w*32+n, k-slot quad): +g*131072 +u*8192 +s8*64
  const uint32_t gbo = (uint32_t)((w * 32 + n) * 512 + quad * 16);

  // ---------------- LDS init ----------------
  {
    f4 z; z[0] = z[1] = z[2] = z[3] = 0.f;
    *reinterpret_cast<f4*>(&smem[LB_H + tid * 16]) = z;   // h0 = 0 (8192 B)
  }
  // enc affine: [w][u][g][n] 16B = WeffT row of zcol
#pragma unroll
  for (int i = 0; i < 2; ++i) {
    int s = tid + i * 512;
    int sw_ = s >> 7, su = (s >> 6) & 1, sg = (s >> 4) & 3, sn = s & 15;
    int zc = sg * 256 + sw_ * 32 + su * 16 + sn;
    *reinterpret_cast<h8*>(&smem[LB_UN + s * 16]) =
        *reinterpret_cast<const h8*>(WeffT + (size_t)zc * 8);
  }
  // LDS B-frag pool: this thread's own frags for s8 = 4 and 6
#pragma unroll
  for (int si = 0; si < 2; ++si) {
    const int s8 = 4 + si * 2;
#pragma unroll
    for (int u = 0; u < 2; ++u)
#pragma unroll
    for (int g = 0; g < 4; ++g) {
      h8 v = GFRAG(s8, u, g);
      *reinterpret_cast<h8*>(
          &smem[LB_BP + (uint32_t)(((w * 16 + si * 8 + u * 4 + g) * 64 + lane) * 16)]) = v;
    }
  }
  // register-resident weights: s8 = 0..3
  h8 Wreg[4][2][4];
#pragma unroll
  for (int s8 = 0; s8 < 4; ++s8)
#pragma unroll
  for (int u = 0; u < 2; ++u)
#pragma unroll
  for (int g = 0; g < 4; ++g)
    Wreg[s8][u][g] = GFRAG(s8, u, g);

  float zb[2][4];
#pragma unroll
  for (int u = 0; u < 2; ++u)
#pragma unroll
  for (int g = 0; g < 4; ++g)
    zb[u][g] = zbias[g * 256 + w * 32 + u * 16 + n];

  f4 cf[2];
#pragma unroll
  for (int u = 0; u < 2; ++u) { cf[u][0] = 0.f; cf[u][1] = 0.f; cf[u][2] = 0.f; cf[u][3] = 0.f; }

  const uint32_t hswz  = (uint32_t)((n & 7) << 4);
  const uint32_t hbase = (uint32_t)(n * 512 + quad * 16);
  const uint32_t bpb   = (uint32_t)(((w * 16) * 64 + lane) * 16);
  const float* prow = pulse + (size_t)(b0 + n) * 1024 * 8;

  __syncthreads();

  // ---------------- encoder: t = 0..1023 ----------------
#pragma unroll 1
  for (int t = 0; t < 1024; ++t) {
    f4 x0, x1;
    x0[0]=x0[1]=x0[2]=x0[3]=0.f; x1[0]=x1[1]=x1[2]=x1[3]=0.f;
    if (quad == 0) {
      const f4* pp = reinterpret_cast<const f4*>(prow + (size_t)t * 8);
      x0 = pp[0]; x1 = pp[1];
    }
    f4 acc[2][4];
#pragma unroll
    for (int u = 0; u < 2; ++u)
#pragma unroll
    for (int g = 0; g < 4; ++g) {
      float z = zb[u][g];
      acc[u][g][0] = z; acc[u][g][1] = z; acc[u][g][2] = z; acc[u][g][3] = z;
    }

    STEP_MFMAS(acc);

    // x-affine (K padded 8->32; only quad0 lanes carry data)
    h8 pa;
#pragma unroll
    for (int j = 0; j < 8; ++j) pa[j] = (_Float16)0.f;
    if (quad == 0) {
      pa[0] = (_Float16)x0[0]; pa[1] = (_Float16)x0[1];
      pa[2] = (_Float16)x0[2]; pa[3] = (_Float16)x0[3];
      pa[4] = (_Float16)x1[0]; pa[5] = (_Float16)x1[1];
      pa[6] = (_Float16)x1[2]; pa[7] = (_Float16)x1[3];
    }
#pragma unroll
    for (int u = 0; u < 2; ++u)
#pragma unroll
    for (int g = 0; g < 4; ++g) {
      h8 af;
#pragma unroll
      for (int j = 0; j < 8; ++j) af[j] = (_Float16)0.f;
      if (quad == 0)
        af = *reinterpret_cast<const h8*>(
            &smem[LB_UN + (uint32_t)(((w * 8 + u * 4 + g) * 16 + n) * 16)]);
      acc[u][g] = __builtin_amdgcn_mfma_f32_16x16x32_f16(pa, af, acc[u][g], 0, 0, 0);
    }

    GATES_AND_STORE(acc);
  }

  // ---------------- decoder setup (overwrites enc_aff union) ----------------
  if (tid < 64) {
    int s8 = tid >> 3, qq = (tid >> 1) & 3, nn = tid & 1;
    h8 v;
#pragma unroll
    for (int j = 0; j < 8; ++j)
      v[j] = WmlpT[nn * 256 + s8 * 32 + qq * 8 + j];
    *reinterpret_cast<h8*>(&smem[LB_WM + tid * 16]) = v;
  }
#pragma unroll
  for (int i = 0; i < 2; ++i) {
    int s = tid + i * 512;
    int sw_ = s >> 7, su = (s >> 6) & 1, sg = (s >> 4) & 3, sn = s & 15;
    int zc = sg * 256 + sw_ * 32 + su * 16 + sn;
    h4 v;
    v[0] = (_Float16)Deff[zc];
    v[1] = (_Float16)Deff[1024 + zc];
    v[2] = (_Float16)dbias[zc];
    v[3] = (_Float16)0.f;
    *reinterpret_cast<h4*>(&smem[LB_DEC + s * 8]) = v;
  }
  if (tid < 16) {
    f2 tk; tk[0] = embed[0]; tk[1] = embed[1];
    *reinterpret_cast<f2*>(&smem[LB_TOK + tid * 8]) = tk;
  }
  const float swv = (n < 2) ? scale_w[n] : 0.f;
  const float sbv = (n < 2) ? scale_b[n] : 0.f;
  const float bmv = (n < 2) ? b_mlp[n]   : 0.f;
  __syncthreads();

  // ---------------- decoder: 35 steps ----------------
#pragma unroll 1
  for (int st = 0; st < 35; ++st) {
    f2 tk = *reinterpret_cast<const f2*>(&smem[LB_TOK + n * 8]);
    f4 acc[2][4];
#pragma unroll
    for (int u = 0; u < 2; ++u)
#pragma unroll
    for (int g = 0; g < 4; ++g) {
      acc[u][g][0] = 0.f; acc[u][g][1] = 0.f; acc[u][g][2] = 0.f; acc[u][g][3] = 0.f;
    }

    STEP_MFMAS(acc);

    // token affine: A = [t0, t1, 1, 0...] (quad0); B rows = [Deff0, Deff1, dbias]
    h8 pa;
#pragma unroll
    for (int j = 0; j < 8; ++j) pa[j] = (_Float16)0.f;
    if (quad == 0) {
      pa[0] = (_Float16)tk[0]; pa[1] = (_Float16)tk[1]; pa[2] = (_Float16)1.f;
    }
#pragma unroll
    for (int u = 0; u < 2; ++u)
#pragma unroll
    for (int g = 0; g < 4; ++g) {
      h8 af;
#pragma unroll
      for (int j = 0; j < 8; ++j) af[j] = (_Float16)0.f;
      if (quad == 0) {
        h4 t4 = *reinterpret_cast<const h4*>(
            &smem[LB_DEC + (uint32_t)(((w * 8 + u * 4 + g) * 16 + n) * 8)]);
        af[0] = t4[0]; af[1] = t4[1]; af[2] = t4[2]; af[3] = t4[3];
      }
      acc[u][g] = __builtin_amdgcn_mfma_f32_16x16x32_f16(pa, af, acc[u][g], 0, 0, 0);
    }

    GATES_AND_STORE(acc);

    // pred_st = h_{st+1} @ W_mlp + b_mlp  (wave 0; h just published)
    if (w == 0) {
      f4 pf; pf[0] = bmv; pf[1] = bmv; pf[2] = bmv; pf[3] = bmv;
#pragma unroll
      for (int s8 = 0; s8 < 8; ++s8) {
        h8 ha = *reinterpret_cast<const h8*>(
            &smem[LB_H + ((hbase + (uint32_t)(s8 * 64)) ^ hswz)]);
        h8 wb;
#pragma unroll
        for (int j = 0; j < 8; ++j) wb[j] = (_Float16)0.f;
        if (n < 2)
          wb = *reinterpret_cast<const h8*>(
              &smem[LB_WM + (uint32_t)((((s8 * 4 + quad) * 2) + n) * 16)]);
        pf = __builtin_amdgcn_mfma_f32_16x16x32_f16(ha, wb, pf, 0, 0, 0);
      }
      if (n < 2) {
#pragma unroll
        for (int r = 0; r < 4; ++r) {
          int row = quad * 4 + r;
          *reinterpret_cast<float*>(&smem[LB_TOK + row * 8 + n * 4]) = pf[r];
          out[((size_t)(b0 + row) * 35 + st) * 2 + n] = pf[r] * swv + sbv;
        }
      }
    }
    __syncthreads();   // tok visible for next iteration
  }
}

extern "C" void kernel_launch(void* const* d_in, const int* in_sizes, int n_in,
                              void* d_out, int out_size, void* d_ws, size_t ws_size,
                              hipStream_t stream) {
  const float* pulse    = (const float*)d_in[0];
  const float* bn_gamma = (const float*)d_in[1];
  const float* bn_beta  = (const float*)d_in[2];
  const float* bn_mean  = (const float*)d_in[3];
  const float* bn_var   = (const float*)d_in[4];
  const float* W_pulse  = (const float*)d_in[5];
  const float* b_pulse  = (const float*)d_in[6];
  const float* lstm_k   = (const float*)d_in[7];
  const float* lstm_rk  = (const float*)d_in[8];
  const float* lstm_b   = (const float*)d_in[9];
  const float* embed    = (const float*)d_in[10];
  const float* W_eis    = (const float*)d_in[11];
  const float* b_eis    = (const float*)d_in[12];
  const float* W_mlp    = (const float*)d_in[13];
  const float* b_mlp    = (const float*)d_in[14];
  const float* scale_w  = (const float*)d_in[15];
  const float* scale_b  = (const float*)d_in[16];

  char* ws = (char*)d_ws;
  _Float16* rkT   = (_Float16*)(ws + WS_RKT);
  _Float16* WeffT = (_Float16*)(ws + WS_WEFF);
  _Float16* WmlpT = (_Float16*)(ws + WS_WMLP);
  float*    Deff  = (float*)(ws + WS_DEFF);
  float*    zbias = (float*)(ws + WS_ZB);
  float*    dbias = (float*)(ws + WS_DB);

  precompute_k<<<1024, 256, 0, stream>>>(bn_gamma, bn_beta, bn_mean, bn_var,
                                         W_pulse, b_pulse, lstm_k, lstm_rk, lstm_b,
                                         W_eis, b_eis, W_mlp,
                                         rkT, WeffT, WmlpT, Deff, zbias, dbias);
  lstm_main_k<<<16, 512, 0, stream>>>(pulse, embed, b_mlp, scale_w, scale_b,
                                      rkT, WeffT, WmlpT, Deff, zbias, dbias,
                                      (float*)d_out);
}

// Round 2
// 4299.656 us; speedup vs baseline: 1.5628x; 1.5628x over previous
//
#include <hip/hip_runtime.h>
#include <cstdint>
#include <cstddef>

// ---------------------------------------------------------------------------
// Trainer_91216515433187: BN + Dense + LSTM encoder (1024 steps) + 35-step
// autoregressive LSTM decoder.
//
// Round 3: one WG (512 thr, 8 waves) per 16 batch rows, no inter-WG traffic.
// Recurrent weights (512KB f16) split: s8 0..4 in regs (160 VGPR/thread),
// s8 6,7 in a 128KB LDS pool, s8 5 streamed from L2 but issued during the
// PREVIOUS step's gates phase (latency hidden) and consumed first.
// x-projection folded in as a 9th K-slot: h LDS is 16x288 in chunk-transposed
// layout (chunk=s8*4+quad, one addr reg + imm offsets, conflict-free b128
// reads). Pulse loaded by wave0 only, one step ahead. zbias added at gate
// time from LDS. Decoder reuses the identical step (slot-8 weights/zb/tok
// swapped at decoder setup); wave0 computes pred in a small post-phase.
// ---------------------------------------------------------------------------

typedef _Float16 h8 __attribute__((ext_vector_type(8)));
typedef float f4 __attribute__((ext_vector_type(4)));

// ws byte offsets (precompute outputs; layout kept)
#define WS_RKT    262400    // 1024 cols x 256 k f16 = 524288 B
#define WS_WEFF   786688    // 1024 cols x 8 f f16 = 16384 B
#define WS_WMLP   803072    // 2 e x 256 k f16 = 1024 B
#define WS_DEFF   804096    // 2 x 1024 f32 = 8192 B
#define WS_ZB     812288    // 1024 f32
#define WS_DB     816384    // 1024 f32

// LDS layout
#define LB_POOL  0          // s8 6,7 pool: [w][fi16][lane64]*16B = 131072
#define LB_P8    131072     // s8 8 quad0-packed: [w][fi8][n16]*16B = 16384
#define LB_ZERO  147456     // 2304 B zeros (quad>=1 slot-8 reads land here)
#define LB_H     149760     // h-ext: 36 chunks x 256B = 9216 (chunks 32..35 = x/zeros)
#define LB_ZB    158976     // 1024 f32 = 4096
#define LDS_SZ   163072

__device__ __forceinline__ float fexp2(float x){
#if __has_builtin(__builtin_amdgcn_exp2f)
  return __builtin_amdgcn_exp2f(x);
#else
  return exp2f(x);
#endif
}
__device__ __forceinline__ float frcp(float x){
#if __has_builtin(__builtin_amdgcn_rcpf)
  return __builtin_amdgcn_rcpf(x);
#else
  return 1.f / x;
#endif
}
__device__ __forceinline__ float sigf(float x){
  return frcp(1.f + fexp2(-1.44269504f * x));
}
__device__ __forceinline__ float tanh_f(float x){
  return 2.f * frcp(1.f + fexp2(-2.88539008f * x)) - 1.f;
}

// grid 1024 x 256 threads  (unchanged — known correct)
__global__ void precompute_k(const float* __restrict__ bn_gamma,
                             const float* __restrict__ bn_beta,
                             const float* __restrict__ bn_mean,
                             const float* __restrict__ bn_var,
                             const float* __restrict__ W_pulse,   // (8,256)
                             const float* __restrict__ b_pulse,   // (256)
                             const float* __restrict__ lstm_k,    // (256,1024)
                             const float* __restrict__ lstm_rk,   // (256,1024)
                             const float* __restrict__ lstm_b,    // (1024)
                             const float* __restrict__ W_eis,     // (2,256)
                             const float* __restrict__ b_eis,     // (256)
                             const float* __restrict__ W_mlp,     // (256,2)
                             _Float16* __restrict__ rkT,          // [col][k]
                             _Float16* __restrict__ WeffT,        // [col][f]
                             _Float16* __restrict__ WmlpT,        // [e][k]
                             float* __restrict__ Deff,            // [e][col]
                             float* __restrict__ zbias,
                             float* __restrict__ dbias)
{
  int gid = blockIdx.x * 256 + threadIdx.x;   // 0..262143
  {
    int col = gid >> 8;
    int k   = gid & 255;
    rkT[col * 256 + k] = (_Float16)lstm_rk[k * 1024 + col];
  }
  if (gid < 512) {
    int e = gid >> 8, k = gid & 255;
    WmlpT[e * 256 + k] = (_Float16)W_mlp[k * 2 + e];
  }
  if (gid < 1024) {
    int j = gid;
    float a[8], bv[8];
#pragma unroll
    for (int f = 0; f < 8; ++f) {
      float af = bn_gamma[f] * rsqrtf(bn_var[f] + 1e-3f);
      a[f]  = af;
      bv[f] = bn_beta[f] - bn_mean[f] * af;
    }
    float m[8] = {0,0,0,0,0,0,0,0};
    float d0 = 0.f, d1 = 0.f, zb2 = 0.f, db2 = 0.f;
    for (int k = 0; k < 256; ++k) {
      float lk = lstm_k[k * 1024 + j];
#pragma unroll
      for (int f = 0; f < 8; ++f) m[f] += W_pulse[f * 256 + k] * lk;
      d0  += W_eis[k]       * lk;
      d1  += W_eis[256 + k] * lk;
      zb2 += b_pulse[k] * lk;
      db2 += b_eis[k]   * lk;
    }
    float zb = lstm_b[j] + zb2;
#pragma unroll
    for (int f = 0; f < 8; ++f) {
      zb += bv[f] * m[f];
      WeffT[j * 8 + f] = (_Float16)(a[f] * m[f]);
    }
    zbias[j] = zb;
    dbias[j] = lstm_b[j] + db2;
    Deff[j]        = d0;
    Deff[1024 + j] = d1;
  }
}

// global weight frag: byte offset into rkT for (col = g*256+w*32+u*16+n, s8, quad)
#define GFRAG(s8_, u_, g_)                                                     \
  (*reinterpret_cast<const h8*>(                                               \
      rkTb + (gbo + (uint32_t)((g_) * 131072 + (u_) * 8192 + (s8_) * 64))))

#define LD_H(s_)                                                               \
  (*reinterpret_cast<const h8*>(&smem[h_rd + (uint32_t)((s_) * 1024)]))

#define MM(ha_, B_)                                                            \
  _Pragma("unroll") for (int u_ = 0; u_ < 2; ++u_)                             \
  _Pragma("unroll") for (int g_ = 0; g_ < 4; ++g_)                             \
    acc[u_][g_] = __builtin_amdgcn_mfma_f32_16x16x32_f16(                      \
        (ha_), (B_)[u_][g_], acc[u_][g_], 0, 0, 0);

#define GQ_LOAD()                                                              \
  _Pragma("unroll") for (int u_ = 0; u_ < 2; ++u_)                             \
  _Pragma("unroll") for (int g_ = 0; g_ < 4; ++g_)                             \
    gq[u_][g_] = GFRAG(5, u_, g_);

#define POOLLD(fi0_)                                                           \
  _Pragma("unroll") for (int u_ = 0; u_ < 2; ++u_)                             \
  _Pragma("unroll") for (int g_ = 0; g_ < 4; ++g_)                             \
    pq[u_][g_] = *reinterpret_cast<const h8*>(                                 \
        &smem[pool_rd + (uint32_t)(((fi0_) + u_ * 4 + g_) * 1024)]);

#define P8LD()                                                                 \
  _Pragma("unroll") for (int u_ = 0; u_ < 2; ++u_)                             \
  _Pragma("unroll") for (int g_ = 0; g_ < 4; ++g_)                             \
    pq[u_][g_] = *reinterpret_cast<const h8*>(                                 \
        &smem[p8_rd + (uint32_t)((u_ * 4 + g_) * 256)]);

// 9-slot MFMA phase: slot5 (gq, preloaded from L2) first, 0..4 regs,
// 6..7 LDS pool, 8 = x/tok affine (quad0-packed, quads>=1 read zeros)
#define STEP_MFMA_PHASE()                                                      \
  {                                                                            \
    h8 a5 = LD_H(5);                                                           \
    h8 a0 = LD_H(0);                                                           \
    MM(a5, gq);                                                                \
    __builtin_amdgcn_sched_barrier(0);                                         \
    h8 pq[2][4];                                                               \
    POOLLD(0);                                                                 \
    h8 a1 = LD_H(1); MM(a0, Wreg[0]);                                          \
    h8 a2 = LD_H(2); MM(a1, Wreg[1]);                                          \
    h8 a3 = LD_H(3); MM(a2, Wreg[2]);                                          \
    h8 a4 = LD_H(4); MM(a3, Wreg[3]);                                          \
    h8 a6 = LD_H(6); MM(a4, Wreg[4]);                                          \
    __builtin_amdgcn_sched_barrier(0);                                         \
    MM(a6, pq);                                                                \
    POOLLD(8);                                                                 \
    h8 a7 = LD_H(7); MM(a7, pq);                                               \
    P8LD();                                                                    \
    h8 a8 = LD_H(8); MM(a8, pq);                                               \
  }

#define GATES_PHASE()                                                          \
  {                                                                            \
    float zb8[2][4];                                                           \
    _Pragma("unroll") for (int u_ = 0; u_ < 2; ++u_)                           \
    _Pragma("unroll") for (int g_ = 0; g_ < 4; ++g_)                           \
      zb8[u_][g_] = *reinterpret_cast<const float*>(                           \
          &smem[zb_rd + (uint32_t)((u_ * 4 + g_) * 64)]);                      \
    _Pragma("unroll") for (int u_ = 0; u_ < 2; ++u_)                           \
    _Pragma("unroll") for (int r_ = 0; r_ < 4; ++r_) {                         \
      float iv = sigf(acc[u_][0][r_] + zb8[u_][0]);                            \
      float fv = sigf(acc[u_][1][r_] + zb8[u_][1]);                            \
      float gv = tanh_f(acc[u_][2][r_] + zb8[u_][2]);                          \
      float ov = sigf(acc[u_][3][r_] + zb8[u_][3]);                            \
      float cc = fv * cf[u_][r_] + iv * gv;                                    \
      cf[u_][r_] = cc;                                                         \
      hv[u_][r_] = (_Float16)(ov * tanh_f(cc));                                \
    }                                                                          \
  }

#define H_STORE()                                                              \
  _Pragma("unroll") for (int u_ = 0; u_ < 2; ++u_)                             \
  _Pragma("unroll") for (int r_ = 0; r_ < 4; ++r_)                             \
    *reinterpret_cast<_Float16*>(&smem[h_wr + (uint32_t)(u_ * 512 + r_ * 16)]) \
        = hv[u_][r_];

// 16 blocks x 512 threads; one block per 16 batch rows; 1 block/CU.
__global__ __launch_bounds__(512, 2)
void lstm_main_k(const float* __restrict__ pulse,      // (256,1024,8)
                 const float* __restrict__ embed,      // (1,2)
                 const float* __restrict__ b_mlp,      // (2)
                 const float* __restrict__ scale_w,    // (2)
                 const float* __restrict__ scale_b,    // (2)
                 const _Float16* __restrict__ rkT,
                 const _Float16* __restrict__ WeffT,
                 const _Float16* __restrict__ WmlpT,
                 const float* __restrict__ Deff,
                 const float* __restrict__ zbias,
                 const float* __restrict__ dbias,
                 float* __restrict__ out)              // (256,35,2)
{
  __shared__ alignas(16) char smem[LDS_SZ];

  const int tid  = threadIdx.x;
  const int w    = tid >> 6;
  const int lane = tid & 63;
  const int n    = lane & 15;
  const int quad = lane >> 4;
  const int b0   = blockIdx.x * 16;

  const char* rkTb = reinterpret_cast<const char*>(rkT);
  const uint32_t gbo = (uint32_t)((w * 32 + n) * 512 + quad * 16);

  // ---------------- LDS init ----------------
  // zero the ZERO block + full h-ext (contiguous 11520 B)
  for (int i = tid; i < 720; i += 512) {
    f4 z; z[0] = z[1] = z[2] = z[3] = 0.f;
    *reinterpret_cast<f4*>(&smem[LB_ZERO + i * 16]) = z;
  }
  // zb (zbias) + slot-8 B-frags (Weff rows), quad0-packed: e = [w][fi][n]
#pragma unroll
  for (int i = 0; i < 2; ++i) {
    int e = tid + i * 512;
    int ew = e >> 7, efi = (e >> 4) & 7, en = e & 15;
    int eu = efi >> 2, eg = efi & 3;
    int col = eg * 256 + ew * 32 + eu * 16 + en;
    *reinterpret_cast<float*>(&smem[LB_ZB + e * 4]) = zbias[col];
    *reinterpret_cast<h8*>(&smem[LB_P8 + e * 16]) =
        *reinterpret_cast<const h8*>(WeffT + (size_t)col * 8);
  }
  // LDS pool: s8 = 6,7
#pragma unroll
  for (int s8 = 6; s8 < 8; ++s8)
#pragma unroll
    for (int u = 0; u < 2; ++u)
#pragma unroll
      for (int g = 0; g < 4; ++g)
        *reinterpret_cast<h8*>(&smem[LB_POOL +
            (uint32_t)(((w * 16 + (s8 - 6) * 8 + u * 4 + g) * 64 + lane) * 16)])
            = GFRAG(s8, u, g);
  // register-resident weights: s8 = 0..4
  h8 Wreg[5][2][4];
#pragma unroll
  for (int s8 = 0; s8 < 5; ++s8)
#pragma unroll
    for (int u = 0; u < 2; ++u)
#pragma unroll
      for (int g = 0; g < 4; ++g)
        Wreg[s8][u][g] = GFRAG(s8, u, g);
  // x(0) into h-ext chunk 32 (wave0 lanes 0..15; row = tid)
  if (tid < 16) {
    const f4* P = reinterpret_cast<const f4*>(pulse + (size_t)(b0 + tid) * 8192);
    f4 xa = P[0], xb = P[1];
    h8 xv;
    xv[0] = (_Float16)xa[0]; xv[1] = (_Float16)xa[1];
    xv[2] = (_Float16)xa[2]; xv[3] = (_Float16)xa[3];
    xv[4] = (_Float16)xb[0]; xv[5] = (_Float16)xb[1];
    xv[6] = (_Float16)xb[2]; xv[7] = (_Float16)xb[3];
    *reinterpret_cast<h8*>(&smem[LB_H + 8192 + tid * 16]) = xv;
  }

  // per-lane addresses
  const uint32_t h_rd    = (uint32_t)(LB_H + quad * 256 + n * 16);
  const uint32_t pool_rd = (uint32_t)(LB_POOL + w * 16384 + lane * 16);
  const uint32_t p8_rd   = (quad == 0)
      ? (uint32_t)(LB_P8 + w * 2048 + n * 16) : (uint32_t)LB_ZERO;
  const uint32_t h_wr    = (uint32_t)(LB_H + (w * 4 + (n >> 3)) * 256 +
                                      quad * 64 + (n & 7) * 2);
  const uint32_t zb_rd   = (uint32_t)(LB_ZB + w * 512 + n * 4);

  f4 cf[2];
#pragma unroll
  for (int u = 0; u < 2; ++u) { cf[u][0]=0.f; cf[u][1]=0.f; cf[u][2]=0.f; cf[u][3]=0.f; }

  // slot-5 fragments for step 0 (L2-resident after init)
  h8 gq[2][4];
  GQ_LOAD();

  const float* prow = pulse + (size_t)(b0 + (tid < 16 ? tid : 0)) * 8192;

  __syncthreads();

  // ---------------- encoder: t = 0..1023 ----------------
#pragma unroll 1
  for (int t = 0; t < 1024; ++t) {
    // pulse prefetch for t+1 (wave0 lanes only)
    f4 px0, px1;
    px0[0]=px0[1]=px0[2]=px0[3]=0.f; px1[0]=px1[1]=px1[2]=px1[3]=0.f;
    if (tid < 16) {
      int tp = (t + 1 < 1024) ? t + 1 : 1023;
      const f4* P = reinterpret_cast<const f4*>(prow + (size_t)tp * 8);
      px0 = P[0]; px1 = P[1];
    }
    f4 acc[2][4];
#pragma unroll
    for (int u = 0; u < 2; ++u)
#pragma unroll
      for (int g = 0; g < 4; ++g) {
        acc[u][g][0]=0.f; acc[u][g][1]=0.f; acc[u][g][2]=0.f; acc[u][g][3]=0.f;
      }
    _Float16 hv[2][4];

    STEP_MFMA_PHASE();
    GQ_LOAD();                       // slot-5 for next step; hides under gates
    __builtin_amdgcn_sched_barrier(0);
    GATES_PHASE();

    __syncthreads();                 // all waves done reading h
    H_STORE();
    if (tid < 16) {
      h8 xv;
      xv[0] = (_Float16)px0[0]; xv[1] = (_Float16)px0[1];
      xv[2] = (_Float16)px0[2]; xv[3] = (_Float16)px0[3];
      xv[4] = (_Float16)px1[0]; xv[5] = (_Float16)px1[1];
      xv[6] = (_Float16)px1[2]; xv[7] = (_Float16)px1[3];
      *reinterpret_cast<h8*>(&smem[LB_H + 8192 + tid * 16]) = xv;
    }
    __syncthreads();                 // h(t+1), x(t+1) visible
  }

  // ---------------- decoder setup ----------------
  // slot-8 weights -> (Deff0, Deff1), zb -> dbias, x-ext -> start token
#pragma unroll
  for (int i = 0; i < 2; ++i) {
    int e = tid + i * 512;
    int ew = e >> 7, efi = (e >> 4) & 7, en = e & 15;
    int eu = efi >> 2, eg = efi & 3;
    int col = eg * 256 + ew * 32 + eu * 16 + en;
    *reinterpret_cast<float*>(&smem[LB_ZB + e * 4]) = dbias[col];
    h8 v;
#pragma unroll
    for (int j = 0; j < 8; ++j) v[j] = (_Float16)0.f;
    v[0] = (_Float16)Deff[col];
    v[1] = (_Float16)Deff[1024 + col];
    *reinterpret_cast<h8*>(&smem[LB_P8 + e * 16]) = v;
  }
  if (tid < 16) {
    h8 xv;
#pragma unroll
    for (int j = 0; j < 8; ++j) xv[j] = (_Float16)0.f;
    xv[0] = (_Float16)embed[0];
    xv[1] = (_Float16)embed[1];
    *reinterpret_cast<h8*>(&smem[LB_H + 8192 + tid * 16]) = xv;
  }
  const float swv = (n < 2) ? scale_w[n] : 0.f;
  const float sbv = (n < 2) ? scale_b[n] : 0.f;
  const float bmv = (n < 2) ? b_mlp[n]   : 0.f;
  __syncthreads();

  // ---------------- decoder: 35 steps ----------------
#pragma unroll 1
  for (int s = 0; s < 35; ++s) {
    f4 acc[2][4];
#pragma unroll
    for (int u = 0; u < 2; ++u)
#pragma unroll
      for (int g = 0; g < 4; ++g) {
        acc[u][g][0]=0.f; acc[u][g][1]=0.f; acc[u][g][2]=0.f; acc[u][g][3]=0.f;
      }
    _Float16 hv[2][4];

    STEP_MFMA_PHASE();
    GQ_LOAD();
    __builtin_amdgcn_sched_barrier(0);
    GATES_PHASE();

    __syncthreads();                 // readers done
    H_STORE();
    __syncthreads();                 // h(s+1) visible

    // pred_s = h(s+1) @ W_mlp + b_mlp (wave0); writes next token + out
    if (w == 0) {
      f4 pf; pf[0] = bmv; pf[1] = bmv; pf[2] = bmv; pf[3] = bmv;
#pragma unroll
      for (int s8 = 0; s8 < 8; ++s8) {
        h8 hv2 = LD_H(s8);
        h8 wb;
#pragma unroll
        for (int j = 0; j < 8; ++j) wb[j] = (_Float16)0.f;
        if (n < 2)
          wb = *reinterpret_cast<const h8*>(WmlpT + n * 256 + s8 * 32 + quad * 8);
        pf = __builtin_amdgcn_mfma_f32_16x16x32_f16(hv2, wb, pf, 0, 0, 0);
      }
      if (n < 2) {
#pragma unroll
        for (int r = 0; r < 4; ++r) {
          int row = quad * 4 + r;
          *reinterpret_cast<_Float16*>(
              &smem[LB_H + 8192 + row * 16 + n * 2]) = (_Float16)pf[r];
          out[((size_t)(b0 + row) * 35 + s) * 2 + n] = pf[r] * swv + sbv;
        }
      }
    }
    __syncthreads();                 // token visible for next step
  }
}

extern "C" void kernel_launch(void* const* d_in, const int* in_sizes, int n_in,
                              void* d_out, int out_size, void* d_ws, size_t ws_size,
                              hipStream_t stream) {
  const float* pulse    = (const float*)d_in[0];
  const float* bn_gamma = (const float*)d_in[1];
  const float* bn_beta  = (const float*)d_in[2];
  const float* bn_mean  = (const float*)d_in[3];
  const float* bn_var   = (const float*)d_in[4];
  const float* W_pulse  = (const float*)d_in[5];
  const float* b_pulse  = (const float*)d_in[6];
  const float* lstm_k   = (const float*)d_in[7];
  const float* lstm_rk  = (const float*)d_in[8];
  const float* lstm_b   = (const float*)d_in[9];
  const float* embed    = (const float*)d_in[10];
  const float* W_eis    = (const float*)d_in[11];
  const float* b_eis    = (const float*)d_in[12];
  const float* W_mlp    = (const float*)d_in[13];
  const float* b_mlp    = (const float*)d_in[14];
  const float* scale_w  = (const float*)d_in[15];
  const float* scale_b  = (const float*)d_in[16];

  char* ws = (char*)d_ws;
  _Float16* rkT   = (_Float16*)(ws + WS_RKT);
  _Float16* WeffT = (_Float16*)(ws + WS_WEFF);
  _Float16* WmlpT = (_Float16*)(ws + WS_WMLP);
  float*    Deff  = (float*)(ws + WS_DEFF);
  float*    zbias = (float*)(ws + WS_ZB);
  float*    dbias = (float*)(ws + WS_DB);

  precompute_k<<<1024, 256, 0, stream>>>(bn_gamma, bn_beta, bn_mean, bn_var,
                                         W_pulse, b_pulse, lstm_k, lstm_rk, lstm_b,
                                         W_eis, b_eis, W_mlp,
                                         rkT, WeffT, WmlpT, Deff, zbias, dbias);
  lstm_main_k<<<16, 512, 0, stream>>>(pulse, embed, b_mlp, scale_w, scale_b,
                                      rkT, WeffT, WmlpT, Deff, zbias, dbias,
                                      (float*)d_out);
}